// Round 11
// baseline (248.259 us; speedup 1.0000x reference)
//
#include <hip/hip_runtime.h>
#include <hip/hip_bf16.h>
#include <cstdint>

#define T_TOK 2048
#define HID   2048
#define NEXP  64
#define TOPK  6
#define NLOC  8
#define ITR   1408
#define ITR2  2816
#define NSLOT (T_TOK * TOPK)
#define KS    32
#define NS1   32    // steps per k-chunk, gemm1 (1024/32)
#define NS2   22    // steps per k-chunk, gemm2 (704/32)
#define KC1   1024  // gemm1 k-chunk
#define KC2   704   // gemm2 k-chunk

// workspace layout (bytes)
#define OFF_CNT   0
#define OFF_CNT2  32
#define OFF_TOPID 4096
#define OFF_TOPW  (OFF_TOPID + T_TOK * TOPK * 4)
#define OFF_TOK   (OFF_TOPW  + T_TOK * TOPK * 4)
#define OFF_WOF   (OFF_TOK   + NSLOT * 4)
#define OFF_XBF   (OFF_WOF   + NSLOT * 4)
#define OFF_ABUF  (OFF_XBF   + (size_t)T_TOK * HID * 2)
#define OFF_HP    (OFF_ABUF  + (size_t)NSLOT * ITR * 2)
#define HP_STRIDE ((size_t)NSLOT * ITR2)   // floats per k-copy

typedef __attribute__((ext_vector_type(4))) float f32x4;
typedef __attribute__((ext_vector_type(8))) short s16x8;
typedef __attribute__((ext_vector_type(4))) short s16x4;

__device__ __forceinline__ short f2bf(float f) {
    union { float f; unsigned u; } v; v.f = f;
    unsigned r = v.u + 0x7FFFu + ((v.u >> 16) & 1u);
    return (short)(r >> 16);
}

// ---------------- prep: zero d_out + counters, cvt x -> bf16 ----------------
__global__ __launch_bounds__(256) void k_prep(const float* __restrict__ x,
                                              short* __restrict__ xbf,
                                              float* __restrict__ out,
                                              int* __restrict__ cnt)
{
    const int r = blockIdx.x;
    const int c = threadIdx.x * 8;
    const float4 a = *(const float4*)&x[(size_t)r * HID + c];
    const float4 b = *(const float4*)&x[(size_t)r * HID + c + 4];
    s16x8 v = { f2bf(a.x), f2bf(a.y), f2bf(a.z), f2bf(a.w),
                f2bf(b.x), f2bf(b.y), f2bf(b.z), f2bf(b.w) };
    *(s16x8*)&xbf[(size_t)r * HID + c] = v;
    float4 z = {0.f, 0.f, 0.f, 0.f};
    *(float4*)&out[(size_t)r * HID + c] = z;
    *(float4*)&out[(size_t)r * HID + c + 4] = z;
    if (r == 0 && threadIdx.x < 16) cnt[threadIdx.x] = 0;
}

// ---------------- routing: softmax + top-6 (stable tie-break) ----------------
__global__ __launch_bounds__(256) void k_route(
    const float* __restrict__ logits, int* __restrict__ cnt,
    int* __restrict__ top_ids, float* __restrict__ top_w)
{
    const int lane = threadIdx.x & 63;
    const int t = blockIdx.x * 4 + (threadIdx.x >> 6);

    float v = logits[t * NEXP + lane];
    float m = v;
    #pragma unroll
    for (int s = 32; s > 0; s >>= 1) m = fmaxf(m, __shfl_xor(m, s));
    float ev = expf(v - m);
    float ssum = ev;
    #pragma unroll
    for (int s = 32; s > 0; s >>= 1) ssum += __shfl_xor(ssum, s);
    float p = ev / ssum;

    float pv = p;
    int ids[TOPK]; float wsel[TOPK]; float wsum = 0.f;
    #pragma unroll
    for (int i = 0; i < TOPK; ++i) {
        float mx = pv;
        #pragma unroll
        for (int s = 32; s > 0; s >>= 1) mx = fmaxf(mx, __shfl_xor(mx, s));
        unsigned long long b = __ballot(pv == mx);
        int idx = (int)__builtin_ctzll(b);
        float w = __shfl(p, idx);
        ids[i] = idx; wsel[i] = w; wsum += w;
        if (lane == idx) pv = -1.0f;
    }
    if (lane < TOPK) {
        top_ids[t * TOPK + lane] = ids[lane];
        top_w[t * TOPK + lane]  = wsel[lane] / wsum;
    }
    if (lane == 0) {
        #pragma unroll
        for (int i = 0; i < TOPK; ++i)
            if ((ids[i] & 7) == 0) atomicAdd(&cnt[ids[i] >> 3], 1);
    }
}

__global__ __launch_bounds__(256) void k_scatter(
    const int* __restrict__ top_ids, const float* __restrict__ top_w,
    const int* __restrict__ cnt, int* __restrict__ cnt2,
    int* __restrict__ tok_of, float* __restrict__ w_of)
{
    const int t = blockIdx.x * 256 + threadIdx.x;
    int offs[NLOC];
    {
        int s = 0;
        #pragma unroll
        for (int i = 0; i < NLOC; ++i) { offs[i] = s; s += cnt[i]; }
    }
    #pragma unroll
    for (int i = 0; i < TOPK; ++i) {
        int id = top_ids[t * TOPK + i];
        if ((id & 7) == 0) {
            int e = id >> 3;
            int s = offs[e] + atomicAdd(&cnt2[e], 1);
            tok_of[s] = t;
            w_of[s]  = top_w[t * TOPK + i];
        }
    }
}

// ---- GEMM1: BM=256, BN=32 pairs, split-K=2, K-step 32, dbuf LDS 40KB ----
// writes fp32 partials (disjoint per k-chunk), silu applied in k_silu
__global__ __launch_bounds__(256, 3) void k_gemm1(
    const short* __restrict__ xbf, const float* __restrict__ w13,
    const float* __restrict__ w13s, const int* __restrict__ cnt,
    const int* __restrict__ tok_of, float* __restrict__ h_part)
{
    const int b = blockIdx.x;
    const int e = b & 7;
    int r = b >> 3;
    const int kc = r & 1; r >>= 1;
    const int nb = r % 44;
    const int m0 = (r / 44) * 256;
    int off_e = 0, cntE = 0;
    #pragma unroll
    for (int i = 0; i < NLOC; ++i) { int c = cnt[i]; if (i < e) off_e += c; if (i == e) cntE = c; }
    if (m0 >= cntE) return;
    const int n0p = nb * 32;
    const int base = off_e + m0;
    const int tid = threadIdx.x;
    const int lane = tid & 63;
    const int wm = tid >> 6;                 // wave owns rows wm*64..+63

    __shared__ __align__(16) short As[2][256 * KS];  // 2x16 KB
    __shared__ __align__(16) short Ws[2][64 * KS];   // 2x4 KB
    __shared__ int tokp[256];

    tokp[tid] = tok_of[base + ((m0 + tid < cntE) ? tid : 0)];
    __syncthreads();

    // A stager: thread = row, 4 chunks of 8 shorts, swizzled
    const short* ag = xbf + (size_t)tokp[tid] * HID + kc * KC1;
    const int abase = tid * KS;
    const int aswz  = (tid & 3) << 3;

    // W stager: 64 rows (32 gate + 32 up) x 32 k-floats; 8 floats/thread
    const int wrow = tid >> 2;               // 0..63
    const int wcol = (tid & 3) * 8;
    const float* wptr = w13 + ((size_t)e * ITR2 +
        (wrow < 32 ? n0p + wrow : ITR + n0p + (wrow - 32))) * HID + kc * KC1 + wcol;
    const int woff  = (wrow * KS + wcol) ^ ((wrow & 3) << 3);
    const int sbase = (e * 22 + (wrow < 32 ? 0 : 11) + (n0p >> 7)) * 16 + kc * 8;

    s16x8 ra[4];
    float4 rw0, rw1;
    float sv;
    f32x4 acc[2][2][4] = {};   // [gate/up][nf][mf]

#define LOADS(s) do {                                                          \
    _Pragma("unroll")                                                          \
    for (int j = 0; j < 4; ++j) ra[j] = *(const s16x8*)(ag + (s) * KS + j * 8);\
    rw0 = *(const float4*)(wptr + (size_t)(s) * 1 * KS);                       \
    rw1 = *(const float4*)(wptr + (size_t)(s) * 1 * KS + 4);                   \
    sv  = w13s[sbase + ((s) >> 2)];                                            \
} while (0)

#define WRITES(bf) do {                                                        \
    _Pragma("unroll")                                                          \
    for (int j = 0; j < 4; ++j) *(s16x8*)&As[bf][(abase + j * 8) ^ aswz] = ra[j]; \
    s16x8 wv = { f2bf(rw0.x * sv), f2bf(rw0.y * sv),                           \
                 f2bf(rw0.z * sv), f2bf(rw0.w * sv),                           \
                 f2bf(rw1.x * sv), f2bf(rw1.y * sv),                           \
                 f2bf(rw1.z * sv), f2bf(rw1.w * sv) };                         \
    *(s16x8*)&Ws[bf][woff] = wv;                                               \
} while (0)

#define COMP(bf) do {                                                          \
    const int co = (lane >> 4) * 8;                                            \
    s16x8 af[4];                                                               \
    _Pragma("unroll")                                                          \
    for (int mf = 0; mf < 4; ++mf) {                                           \
        const int row = wm * 64 + mf * 16 + (lane & 15);                       \
        af[mf] = *(const s16x8*)&As[bf][(row * KS + co) ^ ((row & 3) << 3)];   \
    }                                                                          \
    _Pragma("unroll")                                                          \
    for (int t = 0; t < 2; ++t)                                                \
    _Pragma("unroll")                                                          \
    for (int nf = 0; nf < 2; ++nf) {                                           \
        const int brow = t * 32 + nf * 16 + (lane & 15);                       \
        s16x8 bv = *(const s16x8*)&Ws[bf][(brow * KS + co) ^ ((brow & 3) << 3)]; \
        _Pragma("unroll")                                                      \
        for (int mf = 0; mf < 4; ++mf)                                         \
            acc[t][nf][mf] = __builtin_amdgcn_mfma_f32_16x16x32_bf16(af[mf], bv, acc[t][nf][mf], 0, 0, 0); \
    }                                                                          \
} while (0)

    LOADS(0);
    WRITES(0);
    __syncthreads();
    #pragma unroll 2
    for (int s = 0; s < NS1; ++s) {
        if (s + 1 < NS1) LOADS(s + 1);
        COMP(s & 1);
        if (s + 1 < NS1) {
            WRITES((s + 1) & 1);
            __syncthreads();
        }
    }

    // epilogue: write fp32 partials (disjoint per kc)
    float* hp = h_part + (size_t)kc * HP_STRIDE;
    #pragma unroll
    for (int t = 0; t < 2; ++t)
    #pragma unroll
    for (int nf = 0; nf < 2; ++nf) {
        const int col = t * ITR + n0p + nf * 16 + (lane & 15);
        #pragma unroll
        for (int mf = 0; mf < 4; ++mf)
        #pragma unroll
        for (int j = 0; j < 4; ++j) {
            const int row = wm * 64 + mf * 16 + (lane >> 4) * 4 + j;
            if (m0 + row < cntE)
                hp[(size_t)(base + row) * ITR2 + col] = acc[t][nf][mf][j];
        }
    }
#undef LOADS
#undef WRITES
#undef COMP
}

// ---- silu reduce: a = silu(hg0+hg1) * (hu0+hu1) -> a_buf bf16 ----
__global__ __launch_bounds__(256) void k_silu(
    const float* __restrict__ h_part, const int* __restrict__ cnt,
    short* __restrict__ a_buf)
{
    int total = 0;
    #pragma unroll
    for (int i = 0; i < NLOC; ++i) total += cnt[i];
    const int s = blockIdx.x;
    if (s >= total) return;
    const float* h0 = h_part + (size_t)s * ITR2;
    const float* h1 = h0 + HP_STRIDE;
    short* ao = a_buf + (size_t)s * ITR;
    for (int c = threadIdx.x; c < ITR; c += 256) {
        const float g = h0[c] + h1[c];
        const float u = h0[ITR + c] + h1[ITR + c];
        ao[c] = f2bf((g / (1.f + __expf(-g))) * u);
    }
}

// ---- GEMM2: BM=256, BN=32 out-cols, split-K=2, K-step 32, dbuf LDS 36KB ----
__global__ __launch_bounds__(256, 4) void k_gemm2(
    const short* __restrict__ a_buf, const float* __restrict__ w2,
    const float* __restrict__ w2s, const int* __restrict__ cnt,
    const int* __restrict__ tok_of, const float* __restrict__ w_of,
    float* __restrict__ out)
{
    const int b = blockIdx.x;
    const int e = b & 7;
    int r = b >> 3;
    const int kc = r & 1; r >>= 1;
    const int nb = r % 64;
    const int m0 = (r / 64) * 256;
    int off_e = 0, cntE = 0;
    #pragma unroll
    for (int i = 0; i < NLOC; ++i) { int c = cnt[i]; if (i < e) off_e += c; if (i == e) cntE = c; }
    if (m0 >= cntE) return;
    const int n0 = nb * 32;
    const int base = off_e + m0;
    const int tid = threadIdx.x;
    const int lane = tid & 63;
    const int wm = tid >> 6;

    __shared__ __align__(16) short As[2][256 * KS];  // 2x16 KB
    __shared__ __align__(16) short Ws[2][32 * KS];   // 2x2 KB

    // A stager: thread = row
    int slot = base + tid; if (slot > NSLOT - 1) slot = NSLOT - 1;
    const short* ag = a_buf + (size_t)slot * ITR + kc * KC2;
    const int abase = tid * KS;
    const int aswz  = (tid & 3) << 3;

    // W stager: 32 rows x 32 k-floats; 4 floats/thread
    const int wrow = tid >> 3;               // 0..31
    const int wcol = (tid & 7) * 4;
    const float* wptr = w2 + ((size_t)e * HID + n0 + wrow) * ITR + kc * KC2 + wcol;
    const int woff  = (wrow * KS + wcol) ^ ((wrow & 3) << 3);
    const int sbase = (e * 16 + (n0 >> 7)) * 11;
    const int skoff = kc * KC2;

    s16x8 ra[4];
    float4 rw0;
    float sv;
    f32x4 acc[2][4] = {};   // [nf][mf]

#define LOADS(s) do {                                                          \
    _Pragma("unroll")                                                          \
    for (int j = 0; j < 4; ++j) ra[j] = *(const s16x8*)(ag + (s) * KS + j * 8);\
    rw0 = *(const float4*)(wptr + (size_t)(s) * KS);                           \
    sv  = w2s[sbase + ((skoff + (s) * KS) >> 7)];                              \
} while (0)

#define WRITES(bf) do {                                                        \
    _Pragma("unroll")                                                          \
    for (int j = 0; j < 4; ++j) *(s16x8*)&As[bf][(abase + j * 8) ^ aswz] = ra[j]; \
    s16x4 wv = { f2bf(rw0.x * sv), f2bf(rw0.y * sv),                           \
                 f2bf(rw0.z * sv), f2bf(rw0.w * sv) };                         \
    *(s16x4*)&Ws[bf][woff] = wv;                                               \
} while (0)

#define COMP(bf) do {                                                          \
    const int co = (lane >> 4) * 8;                                            \
    s16x8 af[4];                                                               \
    _Pragma("unroll")                                                          \
    for (int mf = 0; mf < 4; ++mf) {                                           \
        const int row = wm * 64 + mf * 16 + (lane & 15);                       \
        af[mf] = *(const s16x8*)&As[bf][(row * KS + co) ^ ((row & 3) << 3)];   \
    }                                                                          \
    _Pragma("unroll")                                                          \
    for (int nf = 0; nf < 2; ++nf) {                                           \
        const int brow = nf * 16 + (lane & 15);                                \
        s16x8 bv = *(const s16x8*)&Ws[bf][(brow * KS + co) ^ ((brow & 3) << 3)]; \
        _Pragma("unroll")                                                      \
        for (int mf = 0; mf < 4; ++mf)                                         \
            acc[nf][mf] = __builtin_amdgcn_mfma_f32_16x16x32_bf16(af[mf], bv, acc[nf][mf], 0, 0, 0); \
    }                                                                          \
} while (0)

    LOADS(0);
    WRITES(0);
    __syncthreads();
    #pragma unroll 2
    for (int s = 0; s < NS2; ++s) {
        if (s + 1 < NS2) LOADS(s + 1);
        COMP(s & 1);
        if (s + 1 < NS2) {
            WRITES((s + 1) & 1);
            __syncthreads();
        }
    }

    #pragma unroll
    for (int mf = 0; mf < 4; ++mf)
    #pragma unroll
    for (int j = 0; j < 4; ++j) {
        const int row = wm * 64 + mf * 16 + (lane >> 4) * 4 + j;
        if (m0 + row < cntE) {
            const int   t = tok_of[base + row];
            const float w = w_of[base + row];
            #pragma unroll
            for (int nf = 0; nf < 2; ++nf) {
                const int col = n0 + nf * 16 + (lane & 15);
                atomicAdd(&out[(size_t)t * HID + col], acc[nf][mf][j] * w);
            }
        }
    }
#undef LOADS
#undef WRITES
#undef COMP
}

extern "C" void kernel_launch(void* const* d_in, const int* in_sizes, int n_in,
                              void* d_out, int out_size, void* d_ws, size_t ws_size,
                              hipStream_t stream)
{
    const float* x      = (const float*)d_in[0];
    const float* logits = (const float*)d_in[1];
    const float* w13    = (const float*)d_in[2];
    const float* w13s   = (const float*)d_in[3];
    const float* w2     = (const float*)d_in[4];
    const float* w2s    = (const float*)d_in[5];
    float* out = (float*)d_out;
    char*  ws  = (char*)d_ws;

    int*   cnt     = (int*)(ws + OFF_CNT);
    int*   cnt2    = (int*)(ws + OFF_CNT2);
    int*   top_ids = (int*)(ws + OFF_TOPID);
    float* top_w   = (float*)(ws + OFF_TOPW);
    int*   tok_of  = (int*)(ws + OFF_TOK);
    float* w_of    = (float*)(ws + OFF_WOF);
    short* xbf     = (short*)(ws + OFF_XBF);
    short* a_buf   = (short*)(ws + OFF_ABUF);
    float* h_part  = (float*)(ws + OFF_HP);

    k_prep   <<<T_TOK,       256, 0, stream>>>(x, xbf, out, cnt);
    k_route  <<<T_TOK / 4,   256, 0, stream>>>(logits, cnt, top_ids, top_w);
    k_scatter<<<T_TOK / 256, 256, 0, stream>>>(top_ids, top_w, cnt, cnt2, tok_of, w_of);
    // grids: expert in low 3 bits, then k-split, then n, m slowest (live-first)
    k_gemm1  <<<44 * 2 * 2 * 8, 256, 0, stream>>>(xbf, w13, w13s, cnt, tok_of, h_part);
    k_silu   <<<NSLOT,       256, 0, stream>>>(h_part, cnt, a_buf);
    k_gemm2  <<<64 * 2 * 2 * 8, 256, 0, stream>>>(a_buf, w2, w2s, cnt, tok_of, w_of, out);
}

// Round 12
// 192.203 us; speedup vs baseline: 1.2917x; 1.2917x over previous
//
#include <hip/hip_runtime.h>
#include <hip/hip_bf16.h>
#include <cstdint>

#define T_TOK 2048
#define HID   2048
#define NEXP  64
#define TOPK  6
#define NLOC  8
#define ITR   1408
#define ITR2  2816
#define NSLOT (T_TOK * TOPK)
#define NK1   32   // HID/64
#define NK2   22   // ITR/64

// workspace layout (bytes)
#define OFF_CNT   0
#define OFF_CNT2  32
#define OFF_TOPID 4096
#define OFF_TOPW  (OFF_TOPID + T_TOK * TOPK * 4)
#define OFF_TOK   (OFF_TOPW  + T_TOK * TOPK * 4)
#define OFF_WOF   (OFF_TOK   + NSLOT * 4)
#define OFF_XBF   (OFF_WOF   + NSLOT * 4)
#define OFF_ABUF  (OFF_XBF   + (size_t)T_TOK * HID * 2)

typedef __attribute__((ext_vector_type(4))) float f32x4;
typedef __attribute__((ext_vector_type(8))) short s16x8;
typedef __attribute__((ext_vector_type(4))) short s16x4;

__device__ __forceinline__ short f2bf(float f) {
    union { float f; unsigned u; } v; v.f = f;
    unsigned r = v.u + 0x7FFFu + ((v.u >> 16) & 1u);
    return (short)(r >> 16);
}

// one barrier per K-step: drain LDS ops, vmem prefetches stay in flight
#define BAR() do {                                            \
    asm volatile("s_waitcnt lgkmcnt(0)" ::: "memory");        \
    __builtin_amdgcn_s_barrier();                             \
    asm volatile("" ::: "memory");                            \
} while (0)

// ---------------- prep: zero d_out + counters, cvt x -> bf16 ----------------
__global__ __launch_bounds__(256) void k_prep(const float* __restrict__ x,
                                              short* __restrict__ xbf,
                                              float* __restrict__ out,
                                              int* __restrict__ cnt)
{
    const int r = blockIdx.x;
    const int c = threadIdx.x * 8;
    const float4 a = *(const float4*)&x[(size_t)r * HID + c];
    const float4 b = *(const float4*)&x[(size_t)r * HID + c + 4];
    s16x8 v = { f2bf(a.x), f2bf(a.y), f2bf(a.z), f2bf(a.w),
                f2bf(b.x), f2bf(b.y), f2bf(b.z), f2bf(b.w) };
    *(s16x8*)&xbf[(size_t)r * HID + c] = v;
    float4 z = {0.f, 0.f, 0.f, 0.f};
    *(float4*)&out[(size_t)r * HID + c] = z;
    *(float4*)&out[(size_t)r * HID + c + 4] = z;
    if (r == 0 && threadIdx.x < 16) cnt[threadIdx.x] = 0;
}

// ---------------- routing: softmax + top-6 (stable tie-break) ----------------
__global__ __launch_bounds__(256) void k_route(
    const float* __restrict__ logits, int* __restrict__ cnt,
    int* __restrict__ top_ids, float* __restrict__ top_w)
{
    const int lane = threadIdx.x & 63;
    const int t = blockIdx.x * 4 + (threadIdx.x >> 6);

    float v = logits[t * NEXP + lane];
    float m = v;
    #pragma unroll
    for (int s = 32; s > 0; s >>= 1) m = fmaxf(m, __shfl_xor(m, s));
    float ev = expf(v - m);
    float ssum = ev;
    #pragma unroll
    for (int s = 32; s > 0; s >>= 1) ssum += __shfl_xor(ssum, s);
    float p = ev / ssum;

    float pv = p;
    int ids[TOPK]; float wsel[TOPK]; float wsum = 0.f;
    #pragma unroll
    for (int i = 0; i < TOPK; ++i) {
        float mx = pv;
        #pragma unroll
        for (int s = 32; s > 0; s >>= 1) mx = fmaxf(mx, __shfl_xor(mx, s));
        unsigned long long b = __ballot(pv == mx);
        int idx = (int)__builtin_ctzll(b);
        float w = __shfl(p, idx);
        ids[i] = idx; wsel[i] = w; wsum += w;
        if (lane == idx) pv = -1.0f;
    }
    if (lane < TOPK) {
        top_ids[t * TOPK + lane] = ids[lane];
        top_w[t * TOPK + lane]  = wsel[lane] / wsum;
    }
    if (lane == 0) {
        #pragma unroll
        for (int i = 0; i < TOPK; ++i)
            if ((ids[i] & 7) == 0) atomicAdd(&cnt[ids[i] >> 3], 1);
    }
}

__global__ __launch_bounds__(256) void k_scatter(
    const int* __restrict__ top_ids, const float* __restrict__ top_w,
    const int* __restrict__ cnt, int* __restrict__ cnt2,
    int* __restrict__ tok_of, float* __restrict__ w_of)
{
    const int t = blockIdx.x * 256 + threadIdx.x;
    int offs[NLOC];
    {
        int s = 0;
        #pragma unroll
        for (int i = 0; i < NLOC; ++i) { offs[i] = s; s += cnt[i]; }
    }
    #pragma unroll
    for (int i = 0; i < TOPK; ++i) {
        int id = top_ids[t * TOPK + i];
        if ((id & 7) == 0) {
            int e = id >> 3;
            int s = offs[e] + atomicAdd(&cnt2[e], 1);
            tok_of[s] = t;
            w_of[s]  = top_w[t * TOPK + i];
        }
    }
}

// ---- GEMM1: BM=256 (weights once), BN=16 pairs, KS=64 ----
// A: per-wave-private single-buffered 8KB LDS (no barrier); W: dbuf 8KB, 1 BAR/step
__global__ __launch_bounds__(256, 3) void k_gemm1(
    const short* __restrict__ xbf, const float* __restrict__ w13,
    const float* __restrict__ w13s, const int* __restrict__ cnt,
    const int* __restrict__ tok_of, short* __restrict__ a_buf)
{
    const int b = blockIdx.x;
    const int e = b & 7;
    const int r = b >> 3;
    const int nb = r % 88;
    const int m0 = (r / 88) * 256;
    int off_e = 0, cntE = 0;
    #pragma unroll
    for (int i = 0; i < NLOC; ++i) { int c = cnt[i]; if (i < e) off_e += c; if (i == e) cntE = c; }
    if (m0 >= cntE) return;
    const int n0p = nb * 16;
    const int base = off_e + m0;
    const int tid = threadIdx.x;
    const int lane = tid & 63;
    const int wm = tid >> 6;        // wave owns token-rows wm*64..+63

    __shared__ __align__(16) short As[4][64 * 64];   // 32 KB, per-wave private
    __shared__ __align__(16) short Ws[2][32 * 64];   // 8 KB (16 gate + 16 up)
    __shared__ int tokp[256];

    tokp[tid] = tok_of[base + ((m0 + tid < cntE) ? tid : 0)];
    __syncthreads();

    // A stager: wave stages its own 64x64 tile; 8 lanes/row, 16B/lane, coalesced
    unsigned ag[8];   // short-offsets from xbf
    int al[8];
    {
        const int acol = (lane & 7) * 8;
        #pragma unroll
        for (int p = 0; p < 8; ++p) {
            const int row = p * 8 + (lane >> 3);        // wave-local row
            ag[p] = (unsigned)tokp[wm * 64 + row] * HID + acol;
            al[p] = wm * 4096 + ((row * 64 + acol) ^ ((row & 7) << 3));
        }
    }
    // W stager: 32 rows (16 gate + 16 up) x 64 fp32; 8 floats/thread
    const int wrow = tid >> 3;
    const int wcol = (tid & 7) * 8;
    const float* wptr = w13 + ((size_t)e * ITR2 +
        (wrow < 16 ? n0p + wrow : ITR + n0p + (wrow - 16))) * HID + wcol;
    const int woff  = (wrow * 64 + wcol) ^ ((wrow & 7) << 3);
    const int sbase = (e * 22 + (wrow < 16 ? 0 : 11) + (n0p >> 7)) * 16;

    s16x8 ra[8];
    float4 rw0A, rw1A, rw0B, rw1B;   // two W slots (even/odd k)
    float svA, svB;
    f32x4 acc[2][4] = {};            // [gate/up][mf]

#define LOADA(kk) do { const int k0 = min((kk), NK1 - 1) * 64;                 \
    _Pragma("unroll")                                                          \
    for (int p = 0; p < 8; ++p) ra[p] = *(const s16x8*)(xbf + ag[p] + k0);     \
} while (0)

#define WRITEA() do { _Pragma("unroll")                                        \
    for (int p = 0; p < 8; ++p) *(s16x8*)&As[0][al[p]] = ra[p]; } while (0)

#define LOADW(kk, S) do { const int kc = min((kk), NK1 - 1);                   \
    rw0##S = *(const float4*)(wptr + kc * 64);                                 \
    rw1##S = *(const float4*)(wptr + kc * 64 + 4);                             \
    sv##S  = w13s[sbase + (kc >> 1)]; } while (0)

#define WRITEW(bf, S) do {                                                     \
    s16x8 v = { f2bf(rw0##S.x * sv##S), f2bf(rw0##S.y * sv##S),                \
                f2bf(rw0##S.z * sv##S), f2bf(rw0##S.w * sv##S),                \
                f2bf(rw1##S.x * sv##S), f2bf(rw1##S.y * sv##S),                \
                f2bf(rw1##S.z * sv##S), f2bf(rw1##S.w * sv##S) };              \
    *(s16x8*)&Ws[bf][woff] = v; } while (0)

#define COMP(bf) do { _Pragma("unroll")                                        \
    for (int ks = 0; ks < 2; ++ks) {                                           \
        const int co = ks * 32 + (lane >> 4) * 8;                              \
        s16x8 af[4];                                                           \
        _Pragma("unroll")                                                      \
        for (int mf = 0; mf < 4; ++mf) {                                       \
            const int row = mf * 16 + (lane & 15);                             \
            af[mf] = *(const s16x8*)&As[0][wm * 4096 + ((row * 64 + co) ^ ((row & 7) << 3))]; \
        }                                                                      \
        _Pragma("unroll")                                                      \
        for (int t = 0; t < 2; ++t) {                                          \
            const int brow = t * 16 + (lane & 15);                             \
            s16x8 bv = *(const s16x8*)&Ws[bf][(brow * 64 + co) ^ ((brow & 7) << 3)]; \
            _Pragma("unroll")                                                  \
            for (int mf = 0; mf < 4; ++mf)                                     \
                acc[t][mf] = __builtin_amdgcn_mfma_f32_16x16x32_bf16(af[mf], bv, acc[t][mf], 0, 0, 0); \
        } } } while (0)

    // prologue
    LOADA(0); LOADW(0, A);
    WRITEA(); WRITEW(0, A);
    LOADA(1); LOADW(1, B);
    LOADW(2, A);
    BAR();
    // steady state: one barrier per step; A is wave-private (no barrier)
    for (int k = 0; k < NK1 - 2; k += 2) {
        COMP(0); WRITEA(); LOADA(k + 2); WRITEW(1, B); LOADW(k + 3, B); BAR();
        COMP(1); WRITEA(); LOADA(k + 3); WRITEW(0, A); LOADW(k + 4, A); BAR();
    }
    COMP(0); WRITEA(); WRITEW(1, B); BAR();
    COMP(1);

    // epilogue: silu(gate)*up -> a_buf bf16
    {
        const int col = n0p + (lane & 15);
        #pragma unroll
        for (int mf = 0; mf < 4; ++mf)
        #pragma unroll
        for (int j = 0; j < 4; ++j) {
            const int row = wm * 64 + mf * 16 + (lane >> 4) * 4 + j;
            if (m0 + row < cntE) {
                const float g = acc[0][mf][j], u = acc[1][mf][j];
                const float a = (g / (1.f + __expf(-g))) * u;
                a_buf[(size_t)(base + row) * ITR + col] = f2bf(a);
            }
        }
    }
#undef LOADA
#undef WRITEA
#undef LOADW
#undef WRITEW
#undef COMP
}

// ---- GEMM2: BM=256, BN=16 out-cols, KS=64; per-wave A 8KB; W dbuf 4KB ----
__global__ __launch_bounds__(256, 4) void k_gemm2(
    const short* __restrict__ a_buf, const float* __restrict__ w2,
    const float* __restrict__ w2s, const int* __restrict__ cnt,
    const int* __restrict__ tok_of, const float* __restrict__ w_of,
    float* __restrict__ out)
{
    const int b = blockIdx.x;
    const int e = b & 7;
    const int r = b >> 3;
    const int nb = r % 128;
    const int m0 = (r / 128) * 256;
    int off_e = 0, cntE = 0;
    #pragma unroll
    for (int i = 0; i < NLOC; ++i) { int c = cnt[i]; if (i < e) off_e += c; if (i == e) cntE = c; }
    if (m0 >= cntE) return;
    const int n0 = nb * 16;
    const int base = off_e + m0;
    const int tid = threadIdx.x;
    const int lane = tid & 63;
    const int wm = tid >> 6;

    __shared__ __align__(16) short As[4][64 * 64];   // 32 KB per-wave private
    __shared__ __align__(16) short Ws[2][16 * 64];   // 4 KB

    unsigned ag[8];
    int al[8];
    {
        const int acol = (lane & 7) * 8;
        #pragma unroll
        for (int p = 0; p < 8; ++p) {
            const int row = p * 8 + (lane >> 3);
            int slot = base + wm * 64 + row;
            if (slot > NSLOT - 1) slot = NSLOT - 1;
            ag[p] = (unsigned)slot * ITR + acol;
            al[p] = wm * 4096 + ((row * 64 + acol) ^ ((row & 7) << 3));
        }
    }
    // W stager: 16 rows x 64 fp32; 4 floats/thread
    const int wrow = tid >> 4;
    const int wcol = (tid & 15) * 4;
    const float* wptr = w2 + ((size_t)e * HID + n0 + wrow) * ITR + wcol;
    const int woff  = (wrow * 64 + wcol) ^ ((wrow & 7) << 3);
    const int sbase = (e * 16 + (n0 >> 7)) * 11;

    s16x8 ra[8];
    float4 rw0A, rw0B;
    float svA, svB;
    f32x4 acc[4] = {};   // [mf]

#define LOADA(kk) do { const int k0 = min((kk), NK2 - 1) * 64;                 \
    _Pragma("unroll")                                                          \
    for (int p = 0; p < 8; ++p) ra[p] = *(const s16x8*)(a_buf + ag[p] + k0);   \
} while (0)

#define WRITEA() do { _Pragma("unroll")                                        \
    for (int p = 0; p < 8; ++p) *(s16x8*)&As[0][al[p]] = ra[p]; } while (0)

#define LOADW(kk, S) do { const int kc = min((kk), NK2 - 1);                   \
    rw0##S = *(const float4*)(wptr + kc * 64);                                 \
    sv##S  = w2s[sbase + (kc >> 1)]; } while (0)

#define WRITEW(bf, S) do {                                                     \
    s16x4 v = { f2bf(rw0##S.x * sv##S), f2bf(rw0##S.y * sv##S),                \
                f2bf(rw0##S.z * sv##S), f2bf(rw0##S.w * sv##S) };              \
    *(s16x4*)&Ws[bf][woff] = v; } while (0)

#define COMP(bf) do { _Pragma("unroll")                                        \
    for (int ks = 0; ks < 2; ++ks) {                                           \
        const int co = ks * 32 + (lane >> 4) * 8;                              \
        const int brow = lane & 15;                                            \
        s16x8 bv = *(const s16x8*)&Ws[bf][(brow * 64 + co) ^ ((brow & 7) << 3)]; \
        _Pragma("unroll")                                                      \
        for (int mf = 0; mf < 4; ++mf) {                                       \
            const int row = mf * 16 + (lane & 15);                             \
            s16x8 af = *(const s16x8*)&As[0][wm * 4096 + ((row * 64 + co) ^ ((row & 7) << 3))]; \
            acc[mf] = __builtin_amdgcn_mfma_f32_16x16x32_bf16(af, bv, acc[mf], 0, 0, 0); \
        } } } while (0)

    LOADA(0); LOADW(0, A);
    WRITEA(); WRITEW(0, A);
    LOADA(1); LOADW(1, B);
    LOADW(2, A);
    BAR();
    for (int k = 0; k < NK2 - 2; k += 2) {
        COMP(0); WRITEA(); LOADA(k + 2); WRITEW(1, B); LOADW(k + 3, B); BAR();
        COMP(1); WRITEA(); LOADA(k + 3); WRITEW(0, A); LOADW(k + 4, A); BAR();
    }
    COMP(0); WRITEA(); WRITEW(1, B); BAR();
    COMP(1);

    {
        const int col = n0 + (lane & 15);
        #pragma unroll
        for (int mf = 0; mf < 4; ++mf)
        #pragma unroll
        for (int j = 0; j < 4; ++j) {
            const int row = wm * 64 + mf * 16 + (lane >> 4) * 4 + j;
            if (m0 + row < cntE) {
                const int   t = tok_of[base + row];
                const float w = w_of[base + row];
                atomicAdd(&out[(size_t)t * HID + col], acc[mf][j] * w);
            }
        }
    }
#undef LOADA
#undef WRITEA
#undef LOADW
#undef WRITEW
#undef COMP
}

extern "C" void kernel_launch(void* const* d_in, const int* in_sizes, int n_in,
                              void* d_out, int out_size, void* d_ws, size_t ws_size,
                              hipStream_t stream)
{
    const float* x      = (const float*)d_in[0];
    const float* logits = (const float*)d_in[1];
    const float* w13    = (const float*)d_in[2];
    const float* w13s   = (const float*)d_in[3];
    const float* w2     = (const float*)d_in[4];
    const float* w2s    = (const float*)d_in[5];
    float* out = (float*)d_out;
    char*  ws  = (char*)d_ws;

    int*   cnt     = (int*)(ws + OFF_CNT);
    int*   cnt2    = (int*)(ws + OFF_CNT2);
    int*   top_ids = (int*)(ws + OFF_TOPID);
    float* top_w   = (float*)(ws + OFF_TOPW);
    int*   tok_of  = (int*)(ws + OFF_TOK);
    float* w_of    = (float*)(ws + OFF_WOF);
    short* xbf     = (short*)(ws + OFF_XBF);
    short* a_buf   = (short*)(ws + OFF_ABUF);

    k_prep   <<<T_TOK,       256, 0, stream>>>(x, xbf, out, cnt);
    k_route  <<<T_TOK / 4,   256, 0, stream>>>(logits, cnt, top_ids, top_w);
    k_scatter<<<T_TOK / 256, 256, 0, stream>>>(top_ids, top_w, cnt, cnt2, tok_of, w_of);
    // expert in low 3 bits (XCD-pinned); n next; m slowest (live-first)
    k_gemm1  <<<88 * 8 * 8,  256, 0, stream>>>(xbf, w13, w13s, cnt, tok_of, a_buf);
    k_gemm2  <<<128 * 8 * 8, 256, 0, stream>>>(a_buf, w2, w2s, cnt, tok_of, w_of, out);
}

// Round 14
// 161.049 us; speedup vs baseline: 1.5415x; 1.1934x over previous
//
#include <hip/hip_runtime.h>
#include <hip/hip_bf16.h>
#include <cstdint>

#define T_TOK 2048
#define HID   2048
#define NEXP  64
#define TOPK  6
#define NLOC  8
#define ITR   1408
#define ITR2  2816
#define NSLOT (T_TOK * TOPK)
#define KC1   1024  // gemm1 k-chunk (HID/2)
#define KC2   704   // gemm2 k-chunk (ITR/2)
#define NS1   16    // KC1/64
#define NS2   11    // KC2/64

// workspace layout (bytes)
#define OFF_CNT   0
#define OFF_CNT2  32
#define OFF_TOPID 4096
#define OFF_TOPW  (OFF_TOPID + T_TOK * TOPK * 4)
#define OFF_TOK   (OFF_TOPW  + T_TOK * TOPK * 4)
#define OFF_WOF   (OFF_TOK   + NSLOT * 4)
#define OFF_XBF   (OFF_WOF   + NSLOT * 4)
#define OFF_ABUF  (OFF_XBF   + (size_t)T_TOK * HID * 2)
#define OFF_HP    (OFF_ABUF  + (size_t)NSLOT * ITR * 2)
#define HP_STRIDE ((size_t)NSLOT * ITR2)   // floats per k-copy

typedef __attribute__((ext_vector_type(4))) float f32x4;
typedef __attribute__((ext_vector_type(8))) short s16x8;
typedef __attribute__((ext_vector_type(4))) short s16x4;

__device__ __forceinline__ short f2bf(float f) {
    union { float f; unsigned u; } v; v.f = f;
    unsigned r = v.u + 0x7FFFu + ((v.u >> 16) & 1u);
    return (short)(r >> 16);
}

// one barrier per K-step: drain LDS ops; vmem loads stay in flight (counted reg-dep waits)
#define BAR() do {                                            \
    asm volatile("s_waitcnt lgkmcnt(0)" ::: "memory");        \
    __builtin_amdgcn_s_barrier();                             \
    asm volatile("" ::: "memory");                            \
} while (0)

// ---------------- prep: zero d_out + counters, cvt x -> bf16 ----------------
__global__ __launch_bounds__(256) void k_prep(const float* __restrict__ x,
                                              short* __restrict__ xbf,
                                              float* __restrict__ out,
                                              int* __restrict__ cnt)
{
    const int r = blockIdx.x;
    const int c = threadIdx.x * 8;
    const float4 a = *(const float4*)&x[(size_t)r * HID + c];
    const float4 b = *(const float4*)&x[(size_t)r * HID + c + 4];
    s16x8 v = { f2bf(a.x), f2bf(a.y), f2bf(a.z), f2bf(a.w),
                f2bf(b.x), f2bf(b.y), f2bf(b.z), f2bf(b.w) };
    *(s16x8*)&xbf[(size_t)r * HID + c] = v;
    float4 z = {0.f, 0.f, 0.f, 0.f};
    *(float4*)&out[(size_t)r * HID + c] = z;
    *(float4*)&out[(size_t)r * HID + c + 4] = z;
    if (r == 0 && threadIdx.x < 16) cnt[threadIdx.x] = 0;
}

// ---------------- routing: softmax + top-6 (stable tie-break) ----------------
__global__ __launch_bounds__(256) void k_route(
    const float* __restrict__ logits, int* __restrict__ cnt,
    int* __restrict__ top_ids, float* __restrict__ top_w)
{
    const int lane = threadIdx.x & 63;
    const int t = blockIdx.x * 4 + (threadIdx.x >> 6);

    float v = logits[t * NEXP + lane];
    float m = v;
    #pragma unroll
    for (int s = 32; s > 0; s >>= 1) m = fmaxf(m, __shfl_xor(m, s));
    float ev = expf(v - m);
    float ssum = ev;
    #pragma unroll
    for (int s = 32; s > 0; s >>= 1) ssum += __shfl_xor(ssum, s);
    float p = ev / ssum;

    float pv = p;
    int ids[TOPK]; float wsel[TOPK]; float wsum = 0.f;
    #pragma unroll
    for (int i = 0; i < TOPK; ++i) {
        float mx = pv;
        #pragma unroll
        for (int s = 32; s > 0; s >>= 1) mx = fmaxf(mx, __shfl_xor(mx, s));
        unsigned long long b = __ballot(pv == mx);
        int idx = (int)__builtin_ctzll(b);
        float w = __shfl(p, idx);
        ids[i] = idx; wsel[i] = w; wsum += w;
        if (lane == idx) pv = -1.0f;
    }
    if (lane < TOPK) {
        top_ids[t * TOPK + lane] = ids[lane];
        top_w[t * TOPK + lane]  = wsel[lane] / wsum;
    }
    if (lane == 0) {
        #pragma unroll
        for (int i = 0; i < TOPK; ++i)
            if ((ids[i] & 7) == 0) atomicAdd(&cnt[ids[i] >> 3], 1);
    }
}

__global__ __launch_bounds__(256) void k_scatter(
    const int* __restrict__ top_ids, const float* __restrict__ top_w,
    const int* __restrict__ cnt, int* __restrict__ cnt2,
    int* __restrict__ tok_of, float* __restrict__ w_of)
{
    const int t = blockIdx.x * 256 + threadIdx.x;
    int offs[NLOC];
    {
        int s = 0;
        #pragma unroll
        for (int i = 0; i < NLOC; ++i) { offs[i] = s; s += cnt[i]; }
    }
    #pragma unroll
    for (int i = 0; i < TOPK; ++i) {
        int id = top_ids[t * TOPK + i];
        if ((id & 7) == 0) {
            int e = id >> 3;
            int s = offs[e] + atomicAdd(&cnt2[e], 1);
            tok_of[s] = t;
            w_of[s]  = top_w[t * TOPK + i];
        }
    }
}

// ---- GEMM1: BM=256 (weights once), BN=32 pairs, split-K=2, KS=64, 8 waves ----
// A: per-wave-private 4KB strip (no barrier); W: dbuf 16KB bf16, one BAR/step
__global__ __launch_bounds__(512, 4) void k_gemm1(
    const short* __restrict__ xbf, const float* __restrict__ w13,
    const float* __restrict__ w13s, const int* __restrict__ cnt,
    const int* __restrict__ tok_of, float* __restrict__ h_part)
{
    const int b = blockIdx.x;
    const int e = b & 7;
    int t_ = b >> 3;
    const int kc = t_ & 1; t_ >>= 1;
    const int nb = t_ % 44;
    const int m0 = (t_ / 44) * 256;
    int off_e = 0, cntE = 0;
    #pragma unroll
    for (int i = 0; i < NLOC; ++i) { int c = cnt[i]; if (i < e) off_e += c; if (i == e) cntE = c; }
    if (m0 >= cntE) return;
    const int n0p = nb * 32;
    const int base = off_e + m0;
    const int tid = threadIdx.x;
    const int lane = tid & 63;
    const int wm = tid >> 6;          // wave 0..7 owns rows wm*32..+31

    __shared__ __align__(16) short As[8][2048];      // 32 KB: per-wave 32x64 strip
    __shared__ __align__(16) short Ws[2][64 * 64];   // 16 KB: 32 gate + 32 up rows

    // stage token ids through Ws[0] (free until first WRITEW, barriered)
    int* tokp = (int*)&Ws[0][0];
    if (tid < 256) tokp[tid] = tok_of[base + ((m0 + tid < cntE) ? tid : 0)];
    __syncthreads();

    // A stager: 4 loads/thread; load j: row = j*8+(lane>>3), chunk = lane&7 (128B coalesced)
    unsigned ag[4];
    int al[4];
    {
        const int cg = (lane & 7) * 8;
        #pragma unroll
        for (int j = 0; j < 4; ++j) {
            const int row = j * 8 + (lane >> 3);          // wave-local 0..31
            ag[j] = (unsigned)tokp[wm * 32 + row] * HID + (unsigned)(kc * KC1) + cg;
            al[j] = (row * 64 + cg) ^ ((row & 7) << 3);   // row&7 == lane>>3
        }
    }
    __syncthreads();   // done reading tokp; Ws[0] free

    // W stager: 64 rows (32 gate + 32 up) x 64 fp32 per step; 8 floats/thread
    const int wrow = tid >> 3;
    const int wcol = (tid & 7) * 8;
    const float* wptr = w13 + ((size_t)e * ITR2 +
        (wrow < 32 ? n0p + wrow : ITR + n0p + (wrow - 32))) * HID + kc * KC1 + wcol;
    const int woff  = (wrow * 64 + wcol) ^ ((wrow & 7) << 3);
    const int sbase = (e * 22 + (wrow < 32 ? 0 : 11) + (n0p >> 7)) * 16 + kc * 8;

    s16x8 ra[4];
    float4 rw0, rw1;
    float sv;
    f32x4 acc[2][2][2] = {};   // [gate/up][nf][mf]

#define LOADA(kk) do { const int k0 = min((kk), NS1 - 1) * 64;                 \
    _Pragma("unroll")                                                          \
    for (int j = 0; j < 4; ++j) ra[j] = *(const s16x8*)(xbf + ag[j] + k0);     \
} while (0)

#define WRITEA() do { _Pragma("unroll")                                        \
    for (int j = 0; j < 4; ++j) *(s16x8*)&As[wm][al[j]] = ra[j]; } while (0)

#define LOADW(kk) do { const int kq = min((kk), NS1 - 1);                      \
    rw0 = *(const float4*)(wptr + kq * 64);                                    \
    rw1 = *(const float4*)(wptr + kq * 64 + 4);                                \
    sv  = w13s[sbase + (kq >> 1)]; } while (0)

#define WRITEW(bf) do {                                                        \
    s16x8 v = { f2bf(rw0.x * sv), f2bf(rw0.y * sv),                            \
                f2bf(rw0.z * sv), f2bf(rw0.w * sv),                            \
                f2bf(rw1.x * sv), f2bf(rw1.y * sv),                            \
                f2bf(rw1.z * sv), f2bf(rw1.w * sv) };                          \
    *(s16x8*)&Ws[bf][woff] = v; } while (0)

#define COMP(bf) do { _Pragma("unroll")                                        \
    for (int ks = 0; ks < 2; ++ks) {                                           \
        const int co = ks * 32 + (lane >> 4) * 8;                              \
        s16x8 af[2];                                                           \
        _Pragma("unroll")                                                      \
        for (int mf = 0; mf < 2; ++mf) {                                       \
            const int row = mf * 16 + (lane & 15);                             \
            af[mf] = *(const s16x8*)&As[wm][(row * 64 + co) ^ ((row & 7) << 3)]; \
        }                                                                      \
        _Pragma("unroll")                                                      \
        for (int t = 0; t < 2; ++t)                                            \
        _Pragma("unroll")                                                      \
        for (int nf = 0; nf < 2; ++nf) {                                       \
            const int brow = t * 32 + nf * 16 + (lane & 15);                   \
            s16x8 bv = *(const s16x8*)&Ws[bf][(brow * 64 + co) ^ ((brow & 7) << 3)]; \
            _Pragma("unroll")                                                  \
            for (int mf = 0; mf < 2; ++mf)                                     \
                acc[t][nf][mf] = __builtin_amdgcn_mfma_f32_16x16x32_bf16(af[mf], bv, acc[t][nf][mf], 0, 0, 0); \
        } } } while (0)

    // prologue
    LOADA(0); LOADW(0);
    WRITEA(); WRITEW(0);
    LOADA(1); LOADW(1);
    BAR();
    // steady state: one barrier per step; A wave-private, all vmem waits counted
    for (int k = 0; k < NS1 - 1; ++k) {
        COMP(k & 1);
        WRITEA();              // step k+1 A (waits ra reg-dep, vmcnt counted)
        LOADA(k + 2);
        WRITEW((k + 1) & 1);   // step k+1 W (waits rw reg-dep)
        LOADW(k + 2);
        BAR();
    }
    COMP((NS1 - 1) & 1);

    // epilogue: fp32 partials (disjoint per kc)
    float* hp = h_part + (size_t)kc * HP_STRIDE;
    #pragma unroll
    for (int t = 0; t < 2; ++t)
    #pragma unroll
    for (int nf = 0; nf < 2; ++nf) {
        const int col = t * ITR + n0p + nf * 16 + (lane & 15);
        #pragma unroll
        for (int mf = 0; mf < 2; ++mf)
        #pragma unroll
        for (int j = 0; j < 4; ++j) {
            const int row = wm * 32 + mf * 16 + (lane >> 4) * 4 + j;
            if (m0 + row < cntE)
                hp[(size_t)(base + row) * ITR2 + col] = acc[t][nf][mf][j];
        }
    }
#undef LOADA
#undef WRITEA
#undef LOADW
#undef WRITEW
#undef COMP
}

// ---- silu reduce: a = silu(hg0+hg1) * (hu0+hu1) -> a_buf bf16 ----
__global__ __launch_bounds__(256) void k_silu(
    const float* __restrict__ h_part, const int* __restrict__ cnt,
    short* __restrict__ a_buf)
{
    int total = 0;
    #pragma unroll
    for (int i = 0; i < NLOC; ++i) total += cnt[i];
    const int s = blockIdx.x;
    if (s >= total) return;
    const float* h0 = h_part + (size_t)s * ITR2;
    const float* h1 = h0 + HP_STRIDE;
    short* ao = a_buf + (size_t)s * ITR;
    for (int c = threadIdx.x; c < ITR; c += 256) {
        const float g = h0[c] + h1[c];
        const float u = h0[ITR + c] + h1[ITR + c];
        ao[c] = f2bf((g / (1.f + __expf(-g))) * u);
    }
}

// ---- GEMM2: BM=256, BN=32 out-cols, split-K=2, KS=64, 8 waves ----
__global__ __launch_bounds__(512, 4) void k_gemm2(
    const short* __restrict__ a_buf, const float* __restrict__ w2,
    const float* __restrict__ w2s, const int* __restrict__ cnt,
    const int* __restrict__ tok_of, const float* __restrict__ w_of,
    float* __restrict__ out)
{
    const int b = blockIdx.x;
    const int e = b & 7;
    int t_ = b >> 3;
    const int kc = t_ & 1; t_ >>= 1;
    const int nb = t_ % 64;            // FIX R13: 64 n-blocks cover HID=2048
    const int m0 = (t_ / 64) * 256;
    int off_e = 0, cntE = 0;
    #pragma unroll
    for (int i = 0; i < NLOC; ++i) { int c = cnt[i]; if (i < e) off_e += c; if (i == e) cntE = c; }
    if (m0 >= cntE) return;
    const int n0 = nb * 32;
    const int base = off_e + m0;
    const int tid = threadIdx.x;
    const int lane = tid & 63;
    const int wm = tid >> 6;

    __shared__ __align__(16) short As[8][2048];      // 32 KB
    __shared__ __align__(16) short Ws[2][32 * 64];   // 8 KB

    unsigned ag[4];
    int al[4];
    {
        const int cg = (lane & 7) * 8;
        #pragma unroll
        for (int j = 0; j < 4; ++j) {
            const int row = j * 8 + (lane >> 3);
            int slot = base + wm * 32 + row;
            if (slot > NSLOT - 1) slot = NSLOT - 1;
            ag[j] = (unsigned)slot * ITR + (unsigned)(kc * KC2) + cg;
            al[j] = (row * 64 + cg) ^ ((row & 7) << 3);
        }
    }
    // W stager: 32 rows x 64 fp32 per step; 4 floats/thread
    const int wrow = tid >> 4;
    const int wcol = (tid & 15) * 4;
    const float* wptr = w2 + ((size_t)e * HID + n0 + wrow) * ITR + kc * KC2 + wcol;
    const int woff  = (wrow * 64 + wcol) ^ ((wrow & 7) << 3);
    const int sbase = (e * 16 + (n0 >> 7)) * 11;
    const int skoff = kc * KC2;

    s16x8 ra[4];
    float4 rw0;
    float sv;
    f32x4 acc[2][2] = {};   // [nf][mf]

#define LOADA(kk) do { const int k0 = min((kk), NS2 - 1) * 64;                 \
    _Pragma("unroll")                                                          \
    for (int j = 0; j < 4; ++j) ra[j] = *(const s16x8*)(a_buf + ag[j] + k0);   \
} while (0)

#define WRITEA() do { _Pragma("unroll")                                        \
    for (int j = 0; j < 4; ++j) *(s16x8*)&As[wm][al[j]] = ra[j]; } while (0)

#define LOADW(kk) do { const int kq = min((kk), NS2 - 1);                      \
    rw0 = *(const float4*)(wptr + kq * 64);                                    \
    sv  = w2s[sbase + ((skoff + kq * 64) >> 7)]; } while (0)

#define WRITEW(bf) do {                                                        \
    s16x4 v = { f2bf(rw0.x * sv), f2bf(rw0.y * sv),                            \
                f2bf(rw0.z * sv), f2bf(rw0.w * sv) };                          \
    *(s16x4*)&Ws[bf][woff] = v; } while (0)

#define COMP(bf) do { _Pragma("unroll")                                        \
    for (int ks = 0; ks < 2; ++ks) {                                           \
        const int co = ks * 32 + (lane >> 4) * 8;                              \
        s16x8 af[2];                                                           \
        _Pragma("unroll")                                                      \
        for (int mf = 0; mf < 2; ++mf) {                                       \
            const int row = mf * 16 + (lane & 15);                             \
            af[mf] = *(const s16x8*)&As[wm][(row * 64 + co) ^ ((row & 7) << 3)]; \
        }                                                                      \
        _Pragma("unroll")                                                      \
        for (int nf = 0; nf < 2; ++nf) {                                       \
            const int brow = nf * 16 + (lane & 15);                            \
            s16x8 bv = *(const s16x8*)&Ws[bf][(brow * 64 + co) ^ ((brow & 7) << 3)]; \
            _Pragma("unroll")                                                  \
            for (int mf = 0; mf < 2; ++mf)                                     \
                acc[nf][mf] = __builtin_amdgcn_mfma_f32_16x16x32_bf16(af[mf], bv, acc[nf][mf], 0, 0, 0); \
        } } } while (0)

    LOADA(0); LOADW(0);
    WRITEA(); WRITEW(0);
    LOADA(1); LOADW(1);
    BAR();
    for (int k = 0; k < NS2 - 1; ++k) {
        COMP(k & 1);
        WRITEA();
        LOADA(k + 2);
        WRITEW((k + 1) & 1);
        LOADW(k + 2);
        BAR();
    }
    COMP((NS2 - 1) & 1);

    #pragma unroll
    for (int mf = 0; mf < 2; ++mf)
    #pragma unroll
    for (int j = 0; j < 4; ++j) {
        const int row = wm * 32 + mf * 16 + (lane >> 4) * 4 + j;
        if (m0 + row < cntE) {
            const int   t = tok_of[base + row];
            const float w = w_of[base + row];
            #pragma unroll
            for (int nf = 0; nf < 2; ++nf) {
                const int col = n0 + nf * 16 + (lane & 15);
                atomicAdd(&out[(size_t)t * HID + col], acc[nf][mf][j] * w);
            }
        }
    }
#undef LOADA
#undef WRITEA
#undef LOADW
#undef WRITEW
#undef COMP
}

extern "C" void kernel_launch(void* const* d_in, const int* in_sizes, int n_in,
                              void* d_out, int out_size, void* d_ws, size_t ws_size,
                              hipStream_t stream)
{
    const float* x      = (const float*)d_in[0];
    const float* logits = (const float*)d_in[1];
    const float* w13    = (const float*)d_in[2];
    const float* w13s   = (const float*)d_in[3];
    const float* w2     = (const float*)d_in[4];
    const float* w2s    = (const float*)d_in[5];
    float* out = (float*)d_out;
    char*  ws  = (char*)d_ws;

    int*   cnt     = (int*)(ws + OFF_CNT);
    int*   cnt2    = (int*)(ws + OFF_CNT2);
    int*   top_ids = (int*)(ws + OFF_TOPID);
    float* top_w   = (float*)(ws + OFF_TOPW);
    int*   tok_of  = (int*)(ws + OFF_TOK);
    float* w_of    = (float*)(ws + OFF_WOF);
    short* xbf     = (short*)(ws + OFF_XBF);
    short* a_buf   = (short*)(ws + OFF_ABUF);
    float* h_part  = (float*)(ws + OFF_HP);

    k_prep   <<<T_TOK,       256, 0, stream>>>(x, xbf, out, cnt);
    k_route  <<<T_TOK / 4,   256, 0, stream>>>(logits, cnt, top_ids, top_w);
    k_scatter<<<T_TOK / 256, 256, 0, stream>>>(top_ids, top_w, cnt, cnt2, tok_of, w_of);
    // flat ids: e in low 3 bits (XCD round-robin), kc next, n, m slowest (live-first)
    k_gemm1  <<<44 * 2 * 2 * 8, 512, 0, stream>>>(xbf, w13, w13s, cnt, tok_of, h_part);
    k_silu   <<<NSLOT,       256, 0, stream>>>(h_part, cnt, a_buf);
    k_gemm2  <<<64 * 2 * 2 * 8, 512, 0, stream>>>(a_buf, w2, w2s, cnt, tok_of, w_of, out);
}